// Round 5
// baseline (119.172 us; speedup 1.0000x reference)
//
#include <hip/hip_runtime.h>
#include <stdint.h>

#define UNITS 1024
#define BATCH 4096
#define FOURU 4096

typedef __bf16 bf16x8 __attribute__((ext_vector_type(8)));
typedef float f32x4 __attribute__((ext_vector_type(4)));

// round-to-nearest-even f32 -> bf16
__device__ __forceinline__ uint16_t f2bf(float f) {
  uint32_t u = __builtin_bit_cast(uint32_t, f);
  u += 0x7FFFu + ((u >> 16) & 1u);
  return (uint16_t)(u >> 16);
}
__device__ __forceinline__ float bf2f(uint16_t b) {
  uint32_t u = ((uint32_t)b) << 16;
  return __builtin_bit_cast(float, u);
}
__device__ __forceinline__ float fsig(float x) {
  return 1.0f / (1.0f + __expf(-x));
}
__device__ __forceinline__ f32x4 mfma16x16x32(bf16x8 a, bf16x8 b, f32x4 c) {
  return __builtin_amdgcn_mfma_f32_16x16x32_bf16(a, b, c, 0, 0, 0);
}

// async global->LDS, 16B per lane; LDS dest is wave-uniform base + lane*16
__device__ __forceinline__ void gll16(uint16_t* lds, const uint16_t* g) {
  __builtin_amdgcn_global_load_lds(
      (const __attribute__((address_space(1))) uint32_t*)g,
      (__attribute__((address_space(3))) uint32_t*)lds, 16, 0, 0);
}

// Granule swizzle (BK=32 tile = [ROWS][4 granules of 8 bf16]); stored granule
// (row,s) holds global (row, kg = s ^ ((row>>1)&3)). gload_lds dest stays
// LINEAR; permutation lives in per-lane GLOBAL source (rule #21 legal form).
__device__ __forceinline__ int fidx(int row, int l4) {
  return row * 4 + (l4 ^ ((row >> 1) & 3));
}

template <int ROWS>
__device__ __forceinline__ void stage32s(const uint16_t* __restrict__ src,
                                         uint16_t* lds, int tid) {
  const int wb = tid & 192;  // wave*64 granules
#pragma unroll
  for (int p = 0; p < ROWS / 64; ++p) {
    const int gi = p * 256 + tid;
    const int row = gi >> 2;
    const int kg = (gi & 3) ^ ((row >> 1) & 3);
    gll16(lds + (p * 256 + wb) * 8, src + row * UNITS + kg * 8);
  }
}

// ---- prep (fused): blocks [0,4096): h f32->bf16; [4096,8192): R -> RT bf16 ----
__global__ __launch_bounds__(256) void prep_kernel(const float* __restrict__ h32,
                                                   uint16_t* __restrict__ hbf,
                                                   const float* __restrict__ R,
                                                   uint16_t* __restrict__ RT) {
  __shared__ float t[32][33];
  const int b = blockIdx.x;
  if (b < 4096) {
    const int i = (b * 256 + threadIdx.x) * 4;
    float4 v = *(const float4*)(h32 + i);
    ushort4 o;
    o.x = f2bf(v.x); o.y = f2bf(v.y); o.z = f2bf(v.z); o.w = f2bf(v.w);
    *(ushort4*)(hbf + i) = o;
  } else {
    const int bb = b - 4096;
    const int n0 = (bb & 127) * 32, k0 = (bb >> 7) * 32;
    const int tx = threadIdx.x & 31, ty = threadIdx.x >> 5;
#pragma unroll
    for (int i = 0; i < 4; ++i)
      t[ty + i * 8][tx] = R[(size_t)(k0 + ty + i * 8) * FOURU + n0 + tx];
    __syncthreads();
#pragma unroll
    for (int i = 0; i < 4; ++i)
      RT[(size_t)(n0 + ty + i * 8) * UNITS + k0 + tx] = f2bf(t[tx][ty + i * 8]);
  }
}

// ---- s1: m97 structure. BM=BN=128, BK=32, 4 waves of 64x64 (acc 4x4).
//      C = h @ [Rz|Rr]; z=sig(+cz+bz)->zb(bf16); r=sig(+cr+b0); rh=bf16(r*h) ----
__global__ __launch_bounds__(256, 2) void s1_kernel(
    const uint16_t* __restrict__ hbf, const uint16_t* __restrict__ rt,
    const int* __restrict__ idx, const float* __restrict__ kc,
    const float* __restrict__ bz, const float* __restrict__ bias,
    uint16_t* __restrict__ zb, uint16_t* __restrict__ rhb) {
  __shared__ uint16_t sA[2][128 * 32];
  __shared__ uint16_t sB[2][128 * 32];
  const int tid = threadIdx.x;
  const int lane = tid & 63, wave = tid >> 6;
  const int l15 = lane & 15, l4 = lane >> 4;
  // T1 bijective XCD swizzle: nwg=512, q=64; col-major decode (32 rows x 16 cols)
  const int fid = blockIdx.y * 16 + blockIdx.x;
  const int nid = (fid & 7) * 64 + (fid >> 3);
  const int row0 = (nid & 31) * 128;
  const int col0 = (nid >> 5) * 128;
  const int rb = (wave >> 1) * 64, cb = (wave & 1) * 64;
  const uint16_t* pa = hbf + (size_t)row0 * UNITS;
  const uint16_t* pb = rt + (size_t)col0 * UNITS;
  f32x4 acc[4][4] = {};

  stage32s<128>(pa, sA[0], tid);
  stage32s<128>(pb, sB[0], tid);
  __syncthreads();

  int cur = 0;
  for (int t = 0; t < 32; ++t) {
    if (t < 31) {  // issue next-tile loads before compute
      stage32s<128>(pa + (t + 1) * 32, sA[cur ^ 1], tid);
      stage32s<128>(pb + (t + 1) * 32, sB[cur ^ 1], tid);
    }
    const bf16x8* A8 = (const bf16x8*)sA[cur];
    const bf16x8* B8 = (const bf16x8*)sB[cur];
    bf16x8 af[4], bf[4];
#pragma unroll
    for (int m = 0; m < 4; ++m) af[m] = A8[fidx(rb + m * 16 + l15, l4)];
#pragma unroll
    for (int n = 0; n < 4; ++n) bf[n] = B8[fidx(cb + n * 16 + l15, l4)];
#pragma unroll
    for (int m = 0; m < 4; ++m)
#pragma unroll
      for (int n = 0; n < 4; ++n)
        acc[m][n] = mfma16x16x32(af[m], bf[n], acc[m][n]);
    __syncthreads();  // drains next-tile gload_lds; fences buffer swap
    cur ^= 1;
  }

  const bool is_z = (col0 < UNITS);  // block-uniform: col0 multiple of 128
#pragma unroll
  for (int m = 0; m < 4; ++m) {
#pragma unroll
    for (int q = 0; q < 4; ++q) {
      const int i = row0 + rb + m * 16 + l4 * 4 + q;
      const int ch = idx[i];
      const float* kcrow = kc + (size_t)ch * FOURU;
#pragma unroll
      for (int n = 0; n < 4; ++n) {
        const int jc = col0 + cb + n * 16 + l15;
        const float a = acc[m][n][q];
        if (is_z) {
          float z = fsig(a + kcrow[jc] + bz[jc]);
          zb[(size_t)i * UNITS + jc] = f2bf(z);
        } else {
          const int j = jc - UNITS;
          const size_t ij = (size_t)i * UNITS + j;
          float r = fsig(a + kcrow[jc] + bias[j]);
          rhb[ij] = f2bf(r * bf2f(hbf[ij]));
        }
      }
    }
  }
}

// ---- s2/s3 (R4 control structure): BM=64, BK=32, 4 waves of 32x(BN/2) ----
// EPI 1: s2 BN=64: hh=tanh(+ch+b1); hn=z*h+(1-z)*hh -> h_out(f32) + hnb(bf16)
// EPI 2: s3 BN=64: o =tanh(+co+b2) -> o_out(f32)
template <int BN, int EPI>
__global__ __launch_bounds__(256, 4) void gemm_kernel(
    const uint16_t* __restrict__ abf, const uint16_t* __restrict__ bt,
    const int* __restrict__ idx, const float* __restrict__ kc,
    const float* __restrict__ bias, const uint16_t* __restrict__ hbf,
    const uint16_t* __restrict__ zb_in, float* __restrict__ out32,
    uint16_t* __restrict__ outbf) {
  constexpr int NF = BN / 32;
  __shared__ uint16_t sA[2][64 * 32];
  __shared__ uint16_t sB[2][BN * 32];
  const int tid = threadIdx.x;
  const int lane = tid & 63, wave = tid >> 6;
  const int l15 = lane & 15, l4 = lane >> 4;
  // T1: nwg=1024, q=128; col-major decode (64 rows x 16 cols)
  const int fid = blockIdx.y * 16 + blockIdx.x;
  const int nid = (fid & 7) * 128 + (fid >> 3);
  const int row0 = (nid & 63) * 64;
  const int col0 = (nid >> 6) * BN;
  const int wr = wave >> 1, wc = wave & 1;
  const uint16_t* pa = abf + (size_t)row0 * UNITS;
  const uint16_t* pb = bt + (size_t)col0 * UNITS;
  f32x4 acc[2][NF] = {};

  stage32s<64>(pa, sA[0], tid);
  stage32s<BN>(pb, sB[0], tid);
  __syncthreads();

  int cur = 0;
  for (int t = 0; t < 32; ++t) {
    if (t < 31) {
      stage32s<64>(pa + (t + 1) * 32, sA[cur ^ 1], tid);
      stage32s<BN>(pb + (t + 1) * 32, sB[cur ^ 1], tid);
    }
    const bf16x8* A8 = (const bf16x8*)sA[cur];
    const bf16x8* B8 = (const bf16x8*)sB[cur];
    bf16x8 af[2], bf[NF];
#pragma unroll
    for (int m = 0; m < 2; ++m) af[m] = A8[fidx(wr * 32 + m * 16 + l15, l4)];
#pragma unroll
    for (int n = 0; n < NF; ++n)
      bf[n] = B8[fidx(wc * (BN / 2) + n * 16 + l15, l4)];
#pragma unroll
    for (int m = 0; m < 2; ++m)
#pragma unroll
      for (int n = 0; n < NF; ++n)
        acc[m][n] = mfma16x16x32(af[m], bf[n], acc[m][n]);
    __syncthreads();
    cur ^= 1;
  }

#pragma unroll
  for (int m = 0; m < 2; ++m) {
#pragma unroll
    for (int q = 0; q < 4; ++q) {
      const int i = row0 + wr * 32 + m * 16 + l4 * 4 + q;
      const int ch = idx[i];
      const float* kcrow = kc + (size_t)ch * FOURU;
#pragma unroll
      for (int n = 0; n < NF; ++n) {
        const int jc = col0 + wc * (BN / 2) + n * 16 + l15;
        const float a = acc[m][n][q];
        const size_t ij = (size_t)i * UNITS + jc;
        if (EPI == 1) {
          float hh = tanhf(a + kcrow[2 * UNITS + jc] + bias[UNITS + jc]);
          float z = bf2f(zb_in[ij]);
          float hv = bf2f(hbf[ij]);
          float hn = z * hv + (1.0f - z) * hh;
          out32[ij] = hn;
          outbf[ij] = f2bf(hn);
        } else {
          out32[ij] = tanhf(a + kcrow[3 * UNITS + jc] + bias[2 * UNITS + jc]);
        }
      }
    }
  }
}

extern "C" void kernel_launch(void* const* d_in, const int* in_sizes, int n_in,
                              void* d_out, int out_size, void* d_ws, size_t ws_size,
                              hipStream_t stream) {
  const int* idx = (const int*)d_in[0];
  const float* h32 = (const float*)d_in[1];
  const float* R = (const float*)d_in[2];
  const float* kc = (const float*)d_in[3];
  const float* bz = (const float*)d_in[4];
  const float* bias = (const float*)d_in[5];

  float* o_out = (float*)d_out;                  // 4M f32 (output o)
  float* h_out = o_out + (size_t)BATCH * UNITS;  // 4M f32 (output h)

  uint16_t* hbf = (uint16_t*)d_ws;               // bf16(h_tm1)   8 MB
  uint16_t* rt = hbf + (size_t)BATCH * UNITS;    // bf16(R^T)     8 MB
  uint16_t* rhb = rt + (size_t)FOURU * UNITS;    // bf16(r*h)     8 MB
  uint16_t* hnb = rhb + (size_t)BATCH * UNITS;   // bf16(h_new)   8 MB
  uint16_t* zbuf = hnb + (size_t)BATCH * UNITS;  // bf16(z)       8 MB

  prep_kernel<<<dim3(8192), 256, 0, stream>>>(h32, hbf, R, rt);

  // s1: N=2048 z|r GEMM, 128^2 tiles -> grid (16,32)=512
  s1_kernel<<<dim3(16, 32), 256, 0, stream>>>(hbf, rt, idx, kc, bz, bias,
                                              zbuf, rhb);

  // s2: N=1024, BN=64 -> grid (16,64)=1024
  gemm_kernel<64, 1><<<dim3(16, 64), 256, 0, stream>>>(
      rhb, rt + (size_t)2 * UNITS * UNITS, idx, kc, bias, hbf, zbuf, h_out,
      hnb);

  // s3: N=1024, BN=64 -> grid (16,64)=1024
  gemm_kernel<64, 2><<<dim3(16, 64), 256, 0, stream>>>(
      hnb, rt + (size_t)3 * UNITS * UNITS, idx, kc, bias, nullptr, nullptr,
      o_out, nullptr);
}